// Round 10
// baseline (950.570 us; speedup 1.0000x reference)
//
#include <hip/hip_runtime.h>

#define B_  128
#define T_  256
#define D_  256
#define U_  256
#define TU  768      // 3*U
#define TC  64       // timestep chunk
#define NC  (T_/TC)  // 4 chunks

__device__ __forceinline__ float sigm(float x) { return 1.f / (1.f + __expf(-x)); }

// tanh via __expf: tanh(x) = 1 - 2/(e^{2x}+1). (absmax unchanged since R2)
__device__ __forceinline__ float tanh_fast(float x) {
    float e = __expf(2.f * x);
    return 1.f - 2.f / (e + 1.f);
}

// direct cubic B-spline eval: grid cells [g_j, g_j+0.4), g_j = -2.2 + 0.4*j, j=0..10
// nonzero basis m = j-3..j (clipped to 0..7); coeffs at ksw_lds[u*9 + m]
__device__ __forceinline__ float spline_eval(float x, const float* __restrict__ ksw_lds, int u) {
    float xc = (x + 2.2f) * 2.5f;
    float fj = floorf(xc);
    int   j  = (int)fj;
    float tl = xc - fj;
    float t2 = tl * tl, t3 = t2 * tl;
    float om = 1.f - tl;
    const float S = 1.f / 6.f;
    float w0 = om * om * om * S;                            // m = j-3
    float w1 = (3.f * t3 - 6.f * t2 + 4.f) * S;             // m = j-2
    float w2 = (-3.f * t3 + 3.f * t2 + 3.f * tl + 1.f) * S; // m = j-1
    float w3 = t3 * S;                                      // m = j
    bool  v  = (j >= 0) && (j <= 10);
    float r  = 0.f;
#pragma unroll
    for (int k = 0; k < 4; ++k) {
        int   m  = j - 3 + k;
        bool  ok = v && (m >= 0) && (m <= 7);
        int   mc = min(max(m, 0), 7);
        float wk = (k == 0) ? w0 : (k == 1) ? w1 : (k == 2) ? w2 : w3;
        float cf = ksw_lds[u * 9 + mc];
        r += ok ? wk * cf : 0.f;
    }
    return r;
}

// ---------------- K0: zero recurrent state + poison xh tags ----------------
// xh words pre-set to 0x00000001 (tag bit = 1). First expected tags are 0,
// so garbage can never false-match the sentinel poll.
__global__ void k0_init(float* __restrict__ wh, float* __restrict__ wc,
                        float* __restrict__ wsub, float* __restrict__ xh) {
    int i = blockIdx.x * 256 + threadIdx.x;          // grid 128 -> 32768
    wh[i] = 0.f;
    wc[i] = 0.f;
    ((int*)xh)[i]         = 1;
    ((int*)xh)[i + 32768] = 1;
    if (i < 3 * B_) wsub[i] = 0.f;
}

// ---------------- K1: A[b][tl][j] = x[b, t0+tl, :] @ kernel + bias ----------------
// ROUND 10 RETILE: 64(M) x 128(N) tile, 256 threads, 4x8 acc/thread, BK=16.
// Grid (8192/64)x(768/128) = 128x6 = 768 blocks = exactly 3/CU (perfect balance,
// good TLP at ~100 VGPR / 12.8 KB LDS -> 12 waves/CU). Per k: 3 b128 LDS reads
// per 32 FMA (old 64x64: 2 per 16). Col-groups split tx*4 / 64+tx*4 so every
// LDS read is broadcast or 2-way (free per bank rules); old kernel was already
// 2-way. Predicted ~25-30 us vs 57.
__global__ __launch_bounds__(256) void k1_gemm(const float* __restrict__ X,
                                               const float* __restrict__ Km,
                                               const float* __restrict__ bias,
                                               float* __restrict__ A, int t0) {
    __shared__ float Xs[16][68];
    __shared__ float Ks[16][132];
    const int tid = threadIdx.x;
    const int bm  = blockIdx.x * 64;
    const int bn  = blockIdx.y * 128;

    // compute mapping: 16x16 threads; rows m0=ty*4 (4); cols tx*4 and 64+tx*4 (8)
    const int ty = tid >> 4, tx = tid & 15;
    const int m0 = ty * 4,  n0 = tx * 4;

    // X staging: row = tid&63, k-quarter kq = (tid>>6)*4; 1 float4/thread
    const int xr = tid & 63, kq = (tid >> 6) * 4;
    const int rr = bm + xr;
    const float* xrow = X + (size_t)((rr >> 6) * T_ + t0 + (rr & 63)) * D_;

    // K staging: k-row kr = tid>>4, col-group nq = (tid&15)*8; 2 float4/thread
    const int kr = tid >> 4, nq = (tid & 15) * 8;

    float acc[4][8] = {};
    for (int kb = 0; kb < 256; kb += 16) {
        float4 xv = *(const float4*)(xrow + kb + kq);
        Xs[kq + 0][xr] = xv.x;
        Xs[kq + 1][xr] = xv.y;
        Xs[kq + 2][xr] = xv.z;
        Xs[kq + 3][xr] = xv.w;
        *(float4*)&Ks[kr][nq]     = *(const float4*)(Km + (size_t)(kb + kr) * TU + bn + nq);
        *(float4*)&Ks[kr][nq + 4] = *(const float4*)(Km + (size_t)(kb + kr) * TU + bn + nq + 4);
        __syncthreads();
#pragma unroll
        for (int k = 0; k < 16; ++k) {
            float4 av = *(float4*)&Xs[k][m0];          // broadcast (4 addrs/wave)
            float4 b0 = *(float4*)&Ks[k][n0];          // 2-way max
            float4 b1 = *(float4*)&Ks[k][64 + n0];     // 2-way max
            float a[4] = {av.x, av.y, av.z, av.w};
            float bb[8] = {b0.x, b0.y, b0.z, b0.w, b1.x, b1.y, b1.z, b1.w};
#pragma unroll
            for (int i = 0; i < 4; ++i)
#pragma unroll
                for (int j = 0; j < 8; ++j)
                    acc[i][j] = fmaf(a[i], bb[j], acc[i][j]);
        }
        __syncthreads();
    }
    float4 bv0 = *(const float4*)(bias + bn + n0);
    float4 bv1 = *(const float4*)(bias + bn + 64 + n0);
#pragma unroll
    for (int i = 0; i < 4; ++i) {
        float4 o0, o1;
        o0.x = acc[i][0] + bv0.x; o0.y = acc[i][1] + bv0.y;
        o0.z = acc[i][2] + bv0.z; o0.w = acc[i][3] + bv0.w;
        o1.x = acc[i][4] + bv1.x; o1.y = acc[i][5] + bv1.y;
        o1.z = acc[i][6] + bv1.z; o1.w = acc[i][7] + bv1.w;
        *(float4*)(A + (size_t)(bm + m0 + i) * TU + bn + n0)      = o0;
        *(float4*)(A + (size_t)(bm + m0 + i) * TU + bn + 64 + n0) = o1;
    }
}

// ---------------- K2: pair-split recurrence, R stationary in regs ----------------
// R9 structure (141 us, sentinel exchange verified). Round-10 micro only:
//  * poll FIRST in phase CA for waves 6,7 (spin starts ~150 cyc earlier ->
//    shaves ~1 L3 spin quantum on average),
//  * xh publish store issued BEFORE the hs/hhist LDS writes (publish ASAP),
//  * GEMV split into 6 accumulator chains (ILP).
// Sentinel scheme byte-identical to R9 (incl. epilogue tagged publish).
__global__ __launch_bounds__(512, 2)
void k2_rec(const float* __restrict__ A,
            const float* __restrict__ X,
            const float* __restrict__ R,
            const float* __restrict__ stk,
            const float* __restrict__ strk,
            const float* __restrict__ aggw,
            const float* __restrict__ aggb,
            const float* __restrict__ kbw,
            const float* __restrict__ ksw,
            float* __restrict__ out,
            float* __restrict__ ws_h,
            float* __restrict__ ws_c,
            float* __restrict__ ws_sub,
            float* __restrict__ xh,    // [B][2][256], sentinel-tagged
            int t0) {
    __shared__ float hs[256];
    __shared__ float xs[256];
    __shared__ float zred[8][64][3];
    __shared__ float kred[768];
    __shared__ float so_l[3];
    __shared__ float subs[3];
    __shared__ float st2[6];
    __shared__ float hhist[TC][128];        // 32 KB h history -> epilogue bulk write
    __shared__ float ksw_lds[768 * 9];

    const int tid  = threadIdx.x;
    const int lane = tid & 63;
    const int w    = tid >> 6;
    const int p    = w & 3;
    const int c    = ((w >> 2) << 6) | lane;   // 0..127
    const int b    = blockIdx.x & 127;
    const int r    = blockIdx.x >> 7;
    const int ui   = r * 128 + c;              // global output-unit index
    const bool pstate = (p == 0);              // waves 0 and 4 hold gate state

    // ---- stationary R fragment (lives in unified VGPR/AGPR file) ----
    float Rf[3][64];
#pragma unroll
    for (int g = 0; g < 3; ++g)
#pragma unroll
        for (int uu = 0; uu < 64; ++uu)
            Rf[g][uu] = R[(size_t)(p * 64 + uu) * TU + g * 256 + ui];

    // ---- KAN duties: u0 = tid for ALL; u1 + x-prefetch on waves 1,2,3,5 ----
    const int s0 = tid >> 8, d0 = tid & 255;
    const float skx0 = strk[s0 * 512 + d0];
    const float skh0 = strk[s0 * 512 + 256 + d0];
    const float bw0  = kbw[tid];
    int u1i = -1;
    if (tid >= 64 && tid < 256)       u1i = tid - 64;    // waves 1-3 -> 0..191
    else if (tid >= 320 && tid < 384) u1i = tid - 128;   // wave 5    -> 192..255
    float skx1 = 0.f, skh1 = 0.f, bw1 = 0.f;
    if (u1i >= 0) {
        skx1 = strk[2 * 512 + u1i];
        skh1 = strk[2 * 512 + 256 + u1i];
        bw1  = kbw[512 + u1i];
    }

    const float aw0 = aggw[ui], aw1 = aggw[256 + ui], aw2 = aggw[512 + ui], ab = aggb[ui];
    float c_reg = ws_c[b * 256 + ui];

    for (int i = tid; i < 768 * 8; i += 512) ksw_lds[(i >> 3) * 9 + (i & 7)] = ksw[i];
    if (tid < 256) hs[tid] = ws_h[b * 256 + tid];
    if (tid < 256) xs[tid] = X[((size_t)b * T_ + t0) * D_ + tid];
    if (tid < 3)   subs[tid] = ws_sub[b * 3 + tid];
    if (tid < 6)   st2[tid] = stk[tid];

    float az0 = 0.f, az1 = 0.f, az2 = 0.f;     // A(t-1) for gates at CA(tl)
    float xv = 0.f;
    __syncthreads();   // prologue LDS visible

    for (int tl = 0; tl < TC; ++tl) {
        const int t = t0 + tl;

        // ======== phase CA: poll h(t-1) FIRST | gates(t-1)+publish | KAN(t) | x(t+1) ========
        if (tl > 0 && tid >= 384) {               // waves 6,7: sentinel poll = data fetch
            const int uidx = (1 - r) * 128 + (tid - 384);
            const unsigned expect = (unsigned)(((t - 1) >> 1) & 1);
            const unsigned* src = (const unsigned*)&xh[((size_t)b * 2 + ((t - 1) & 1)) * 256 + uidx];
            unsigned v;
            do {
                v = __hip_atomic_load(src, __ATOMIC_RELAXED, __HIP_MEMORY_SCOPE_SYSTEM);
            } while ((v & 1u) != expect);
            hs[uidx] = __uint_as_float(v);
        }
        if (pstate) {
            if (tl > 0) {
                float z0 = az0, z1 = az1, z2 = az2;
#pragma unroll
                for (int q = 0; q < 4; ++q) {
                    z0 += zred[w + q][lane][0];
                    z1 += zred[w + q][lane][1];
                    z2 += zred[w + q][lane][2];
                }
                float ig = sigm(z0);
                float fg = sigm(z1);
                c_reg = fg * c_reg + ig * tanh_fast(z2);
                float og = sigm(so_l[0] * aw0 + so_l[1] * aw1 + so_l[2] * aw2 + ab);
                float hn = og * tanh_fast(c_reg);
                // sentinel publish FIRST (partner is spinning on this word):
                // low mantissa bit := (s>>1)&1, s = t-1. Fire-and-forget.
                unsigned hb = (__float_as_uint(hn) & ~1u) | (unsigned)(((t - 1) >> 1) & 1);
                __hip_atomic_store((unsigned*)&xh[((size_t)b * 2 + ((t - 1) & 1)) * 256 + ui],
                                   hb, __ATOMIC_RELAXED, __HIP_MEMORY_SCOPE_SYSTEM);
                hs[ui] = hn;
                hhist[tl - 1][c] = hn;
            }
            // A(t) prefetch for gates at CA(tl+1)
            const float* Ap = A + ((size_t)b * TC + tl) * TU + ui;
            az0 = Ap[0]; az1 = Ap[256]; az2 = Ap[512];
        }
        if (u1i >= 0) {                           // x(t+1) issue (stage at B)
            int tn = (t + 1 < T_) ? t + 1 : t;
            xv = X[((size_t)b * T_ + tn) * D_ + u1i];
        }
        {                                         // KAN u0 (reads xs(t), subs)
            float a0 = xs[d0] * skx0 + subs[s0] * skh0;
            kred[tid] = a0 * sigm(a0) * bw0 + spline_eval(a0, ksw_lds, tid);
        }
        if (u1i >= 0) {                           // KAN u1
            float a1 = xs[u1i] * skx1 + subs[2] * skh1;
            kred[512 + u1i] = a1 * sigm(a1) * bw1 + spline_eval(a1, ksw_lds, 512 + u1i);
        }
        __syncthreads();   // syncCA: hs(t-1) complete + kred visible

        // ======== phase B: GEMV(t) | KAN reduce(t) | stage xs(t+1) ========
        {
            const float* hp = &hs[p * 64];
            float a0 = 0.f, a1 = 0.f, a2 = 0.f;
            float b0 = 0.f, b1 = 0.f, b2 = 0.f;   // 6 chains for ILP
#pragma unroll
            for (int j = 0; j < 8; ++j) {
                float4 h4 = *(const float4*)(hp + j * 8);       // uniform -> broadcast
                float4 h5 = *(const float4*)(hp + j * 8 + 4);
                a0 = fmaf(h4.x, Rf[0][j * 8 + 0], a0);
                a1 = fmaf(h4.x, Rf[1][j * 8 + 0], a1);
                a2 = fmaf(h4.x, Rf[2][j * 8 + 0], a2);
                b0 = fmaf(h4.y, Rf[0][j * 8 + 1], b0);
                b1 = fmaf(h4.y, Rf[1][j * 8 + 1], b1);
                b2 = fmaf(h4.y, Rf[2][j * 8 + 1], b2);
                a0 = fmaf(h4.z, Rf[0][j * 8 + 2], a0);
                a1 = fmaf(h4.z, Rf[1][j * 8 + 2], a1);
                a2 = fmaf(h4.z, Rf[2][j * 8 + 2], a2);
                b0 = fmaf(h4.w, Rf[0][j * 8 + 3], b0);
                b1 = fmaf(h4.w, Rf[1][j * 8 + 3], b1);
                b2 = fmaf(h4.w, Rf[2][j * 8 + 3], b2);
                a0 = fmaf(h5.x, Rf[0][j * 8 + 4], a0);
                a1 = fmaf(h5.x, Rf[1][j * 8 + 4], a1);
                a2 = fmaf(h5.x, Rf[2][j * 8 + 4], a2);
                b0 = fmaf(h5.y, Rf[0][j * 8 + 5], b0);
                b1 = fmaf(h5.y, Rf[1][j * 8 + 5], b1);
                b2 = fmaf(h5.y, Rf[2][j * 8 + 5], b2);
                a0 = fmaf(h5.z, Rf[0][j * 8 + 6], a0);
                a1 = fmaf(h5.z, Rf[1][j * 8 + 6], a1);
                a2 = fmaf(h5.z, Rf[2][j * 8 + 6], a2);
                b0 = fmaf(h5.w, Rf[0][j * 8 + 7], b0);
                b1 = fmaf(h5.w, Rf[1][j * 8 + 7], b1);
                b2 = fmaf(h5.w, Rf[2][j * 8 + 7], b2);
            }
            zred[w][lane][0] = a0 + b0;
            zred[w][lane][1] = a1 + b1;
            zred[w][lane][2] = a2 + b2;
        }
        if (w < 3) {                              // KAN reduce (kred from syncCA)
            float v = kred[w * 256 + lane] + kred[w * 256 + 64 + lane]
                    + kred[w * 256 + 128 + lane] + kred[w * 256 + 192 + lane];
#pragma unroll
            for (int m = 32; m > 0; m >>= 1) v += __shfl_xor(v, m, 64);
            if (lane == 0) {
                so_l[w] = v;
                subs[w] = st2[w * 2] * v + st2[w * 2 + 1] * subs[w];
            }
        }
        if (u1i >= 0) xs[u1i] = xv;               // stage x(t+1)
        __syncthreads();   // syncB: zred/so_l/subs/xs(t+1) visible
    }

    // ---- epilogue: final gates (step s = t0+TC-1), then bulk out-write ----
    if (pstate) {
        float z0 = az0, z1 = az1, z2 = az2;       // az = A(t0+TC-1)
#pragma unroll
        for (int q = 0; q < 4; ++q) {
            z0 += zred[w + q][lane][0];
            z1 += zred[w + q][lane][1];
            z2 += zred[w + q][lane][2];
        }
        float ig = sigm(z0);
        float fg = sigm(z1);
        c_reg = fg * c_reg + ig * tanh_fast(z2);
        float og = sigm(so_l[0] * aw0 + so_l[1] * aw1 + so_l[2] * aw2 + ab);
        float hn = og * tanh_fast(c_reg);
        hhist[TC - 1][c] = hn;
        ws_h[b * 256 + ui] = hn;                  // exact value for next chunk's prologue
        ws_c[b * 256 + ui] = c_reg;
        // tagged publish of h(t0+TC-1) keeps per-word tag alternation unbroken
        // across chunk boundaries (R9 fix -- REQUIRED for correctness).
        {
            const int s = t0 + TC - 1;
            unsigned hb = (__float_as_uint(hn) & ~1u) | (unsigned)(((s) >> 1) & 1);
            __hip_atomic_store((unsigned*)&xh[((size_t)b * 2 + (s & 1)) * 256 + ui],
                               hb, __ATOMIC_RELAXED, __HIP_MEMORY_SCOPE_SYSTEM);
        }
    }
    __syncthreads();
    for (int i = tid; i < TC * 128; i += 512) {
        int tl = i >> 7, cc = i & 127;
        out[((size_t)b * T_ + t0 + tl) * U_ + r * 128 + cc] = hhist[tl][cc];
    }
    if (tid < 3) ws_sub[b * 3 + tid] = subs[tid];
}

extern "C" void kernel_launch(void* const* d_in, const int* in_sizes, int n_in,
                              void* d_out, int out_size, void* d_ws, size_t ws_size,
                              hipStream_t stream) {
    const float* x    = (const float*)d_in[0];
    const float* Kmat = (const float*)d_in[1];
    const float* R    = (const float*)d_in[2];
    const float* bias = (const float*)d_in[3];
    const float* stk  = (const float*)d_in[4];
    const float* strk = (const float*)d_in[5];
    const float* aggw = (const float*)d_in[6];
    const float* aggb = (const float*)d_in[7];
    const float* kbw  = (const float*)d_in[8];
    const float* ksw  = (const float*)d_in[9];
    float* out = (float*)d_out;

    float* ws   = (float*)d_ws;
    float* A    = ws;                             // 6,291,456 floats (24 MB)
    float* wh   = A + (size_t)B_ * TC * TU;       // 32768
    float* wc   = wh + B_ * U_;                   // 32768
    float* wsub = wc + B_ * U_;                   // 384 (pad to 512)
    float* xh   = wsub + 512;                     // B*2*256 = 65536

    k0_init<<<dim3(B_), dim3(256), 0, stream>>>(wh, wc, wsub, xh);
    for (int ci = 0; ci < NC; ++ci) {
        k1_gemm<<<dim3((B_ * TC) / 64, TU / 128), dim3(256), 0, stream>>>(x, Kmat, bias, A, ci * TC);
        k2_rec<<<dim3(2 * B_), dim3(512), 0, stream>>>(A, x, R, stk, strk, aggw, aggb, kbw, ksw,
                                                       out, wh, wc, wsub, xh, ci * TC);
    }
}

// Round 11
// 897.450 us; speedup vs baseline: 1.0592x; 1.0592x over previous
//
#include <hip/hip_runtime.h>

#define B_  128
#define T_  256
#define D_  256
#define U_  256
#define TU  768      // 3*U
#define TC  64       // timestep chunk
#define NC  (T_/TC)  // 4 chunks

__device__ __forceinline__ float sigm(float x) { return 1.f / (1.f + __expf(-x)); }

// tanh via __expf: tanh(x) = 1 - 2/(e^{2x}+1). (absmax unchanged since R2)
__device__ __forceinline__ float tanh_fast(float x) {
    float e = __expf(2.f * x);
    return 1.f - 2.f / (e + 1.f);
}

// direct cubic B-spline eval: grid cells [g_j, g_j+0.4), g_j = -2.2 + 0.4*j, j=0..10
// nonzero basis m = j-3..j (clipped to 0..7); coeffs at ksw_lds[u*9 + m]
__device__ __forceinline__ float spline_eval(float x, const float* __restrict__ ksw_lds, int u) {
    float xc = (x + 2.2f) * 2.5f;
    float fj = floorf(xc);
    int   j  = (int)fj;
    float tl = xc - fj;
    float t2 = tl * tl, t3 = t2 * tl;
    float om = 1.f - tl;
    const float S = 1.f / 6.f;
    float w0 = om * om * om * S;                            // m = j-3
    float w1 = (3.f * t3 - 6.f * t2 + 4.f) * S;             // m = j-2
    float w2 = (-3.f * t3 + 3.f * t2 + 3.f * tl + 1.f) * S; // m = j-1
    float w3 = t3 * S;                                      // m = j
    bool  v  = (j >= 0) && (j <= 10);
    float r  = 0.f;
#pragma unroll
    for (int k = 0; k < 4; ++k) {
        int   m  = j - 3 + k;
        bool  ok = v && (m >= 0) && (m <= 7);
        int   mc = min(max(m, 0), 7);
        float wk = (k == 0) ? w0 : (k == 1) ? w1 : (k == 2) ? w2 : w3;
        float cf = ksw_lds[u * 9 + mc];
        r += ok ? wk * cf : 0.f;
    }
    return r;
}

// ---------------- K0: zero recurrent state + poison xh tags ----------------
__global__ void k0_init(float* __restrict__ wh, float* __restrict__ wc,
                        float* __restrict__ wsub, float* __restrict__ xh) {
    int i = blockIdx.x * 256 + threadIdx.x;          // grid 128 -> 32768
    wh[i] = 0.f;
    wc[i] = 0.f;
    ((int*)xh)[i]         = 1;
    ((int*)xh)[i + 32768] = 1;
    if (i < 3 * B_) wsub[i] = 0.f;
}

// ---------------- K1: A[b][tl][j] = x[b, t0+tl, :] @ kernel + bias ----------------
// ROUND 11 RETILE: 64(M) x 192(N) tile, 128 threads (2 waves), 8x12 acc/thread.
// Grid = (8192/64) x (768/192) = 128x4 = 512 blocks = 2 independent blocks/CU.
// Why: k1 is LDS-read-throughput-bound (b128 ~12cyc CU-serialized). Old 4x8 acc
// = 3 reads per 32 FMA -> 44% FMA util (53us). 8x12 = 5 reads per 96 FMA -> ~80%.
// R7 tried 8x12 with 256-thr blocks (grid 256 = 1 block/CU) and lost to exposed
// staging barriers; 2 blocks/CU lets one block's staging overlap the other's FMA.
__global__ __launch_bounds__(128, 1) void k1_gemm(const float* __restrict__ X,
                                                  const float* __restrict__ Km,
                                                  const float* __restrict__ bias,
                                                  float* __restrict__ A, int t0) {
    __shared__ float Xs[16][68];    // 4.3 KB
    __shared__ float Ks[16][196];   // 12.5 KB
    const int tid = threadIdx.x;
    const int bm  = blockIdx.x * 64;
    const int bn  = blockIdx.y * 192;

    // compute mapping: 8x16 thread grid; each thread 8 rows x 12 cols
    const int ty = tid >> 4, tx = tid & 15;
    const int m0 = ty * 8, n0 = tx * 12;

    // X staging: row xr = tid&63, k-half kq = (tid>>6)*8; 2 float4 loads
    const int xr = tid & 63, kq = (tid >> 6) * 8;
    const int rr = bm + xr;
    const float* xrow = X + (size_t)((rr >> 6) * T_ + t0 + (rr & 63)) * D_;

    // K staging: k-row kr = tid>>3 (0..15), col group nq = (tid&7)*24; 6 float4
    const int kr = tid >> 3, nq = (tid & 7) * 24;

    float acc[8][12] = {};
    for (int kb = 0; kb < 256; kb += 16) {
        float4 xv0 = *(const float4*)(xrow + kb + kq);
        float4 xv1 = *(const float4*)(xrow + kb + kq + 4);
        Xs[kq + 0][xr] = xv0.x; Xs[kq + 1][xr] = xv0.y;
        Xs[kq + 2][xr] = xv0.z; Xs[kq + 3][xr] = xv0.w;
        Xs[kq + 4][xr] = xv1.x; Xs[kq + 5][xr] = xv1.y;
        Xs[kq + 6][xr] = xv1.z; Xs[kq + 7][xr] = xv1.w;
#pragma unroll
        for (int i = 0; i < 6; ++i)
            *(float4*)&Ks[kr][nq + i * 4] =
                *(const float4*)(Km + (size_t)(kb + kr) * TU + bn + nq + i * 4);
        __syncthreads();
#pragma unroll 4
        for (int k = 0; k < 16; ++k) {
            float a[8], bb[12];
            *(float4*)&a[0]  = *(const float4*)&Xs[k][m0];       // 8 distinct addrs/wave
            *(float4*)&a[4]  = *(const float4*)&Xs[k][m0 + 4];
            *(float4*)&bb[0] = *(const float4*)&Ks[k][n0];       // <=2-way banks
            *(float4*)&bb[4] = *(const float4*)&Ks[k][n0 + 4];
            *(float4*)&bb[8] = *(const float4*)&Ks[k][n0 + 8];
#pragma unroll
            for (int i = 0; i < 8; ++i)
#pragma unroll
                for (int j = 0; j < 12; ++j)
                    acc[i][j] = fmaf(a[i], bb[j], acc[i][j]);
        }
        __syncthreads();
    }
#pragma unroll
    for (int j4 = 0; j4 < 3; ++j4) {
        float4 bv = *(const float4*)(bias + bn + n0 + j4 * 4);
#pragma unroll
        for (int i = 0; i < 8; ++i) {
            float4 o;
            o.x = acc[i][j4 * 4 + 0] + bv.x;
            o.y = acc[i][j4 * 4 + 1] + bv.y;
            o.z = acc[i][j4 * 4 + 2] + bv.z;
            o.w = acc[i][j4 * 4 + 3] + bv.w;
            *(float4*)(A + (size_t)(bm + m0 + i) * TU + bn + n0 + j4 * 4) = o;
        }
    }
}

// ---------------- K2: pair-split recurrence, R stationary in regs ----------------
// BYTE-EXACT revert to the verified R9 kernel (141 us, VALUBusy 47%).
// R10's "micro-opts" regressed it to 182: poll-first serialized the polling
// waves' KAN eval AFTER the spin (R9 overlaps it DURING the partner's publish
// flight); publish-reorder + 6-chain GEMV didn't compensate. Lesson kept in
// this comment; code below is R9 verbatim.
__global__ __launch_bounds__(512, 2)
void k2_rec(const float* __restrict__ A,
            const float* __restrict__ X,
            const float* __restrict__ R,
            const float* __restrict__ stk,
            const float* __restrict__ strk,
            const float* __restrict__ aggw,
            const float* __restrict__ aggb,
            const float* __restrict__ kbw,
            const float* __restrict__ ksw,
            float* __restrict__ out,
            float* __restrict__ ws_h,
            float* __restrict__ ws_c,
            float* __restrict__ ws_sub,
            float* __restrict__ xh,    // [B][2][256], sentinel-tagged
            int t0) {
    __shared__ float hs[256];
    __shared__ float xs[256];
    __shared__ float zred[8][64][3];
    __shared__ float kred[768];
    __shared__ float so_l[3];
    __shared__ float subs[3];
    __shared__ float st2[6];
    __shared__ float hhist[TC][128];        // 32 KB h history -> epilogue bulk write
    __shared__ float ksw_lds[768 * 9];

    const int tid  = threadIdx.x;
    const int lane = tid & 63;
    const int w    = tid >> 6;
    const int p    = w & 3;
    const int c    = ((w >> 2) << 6) | lane;   // 0..127
    const int b    = blockIdx.x & 127;
    const int r    = blockIdx.x >> 7;
    const int ui   = r * 128 + c;              // global output-unit index
    const bool pstate = (p == 0);              // waves 0 and 4 hold gate state

    // ---- stationary R fragment (lives in unified VGPR/AGPR file) ----
    float Rf[3][64];
#pragma unroll
    for (int g = 0; g < 3; ++g)
#pragma unroll
        for (int uu = 0; uu < 64; ++uu)
            Rf[g][uu] = R[(size_t)(p * 64 + uu) * TU + g * 256 + ui];

    // ---- KAN duties: u0 = tid for ALL; u1 + x-prefetch on waves 1,2,3,5 ----
    const int s0 = tid >> 8, d0 = tid & 255;
    const float skx0 = strk[s0 * 512 + d0];
    const float skh0 = strk[s0 * 512 + 256 + d0];
    const float bw0  = kbw[tid];
    int u1i = -1;
    if (tid >= 64 && tid < 256)       u1i = tid - 64;    // waves 1-3 -> 0..191
    else if (tid >= 320 && tid < 384) u1i = tid - 128;   // wave 5    -> 192..255
    float skx1 = 0.f, skh1 = 0.f, bw1 = 0.f;
    if (u1i >= 0) {
        skx1 = strk[2 * 512 + u1i];
        skh1 = strk[2 * 512 + 256 + u1i];
        bw1  = kbw[512 + u1i];
    }

    const float aw0 = aggw[ui], aw1 = aggw[256 + ui], aw2 = aggw[512 + ui], ab = aggb[ui];
    float c_reg = ws_c[b * 256 + ui];

    for (int i = tid; i < 768 * 8; i += 512) ksw_lds[(i >> 3) * 9 + (i & 7)] = ksw[i];
    if (tid < 256) hs[tid] = ws_h[b * 256 + tid];
    if (tid < 256) xs[tid] = X[((size_t)b * T_ + t0) * D_ + tid];
    if (tid < 3)   subs[tid] = ws_sub[b * 3 + tid];
    if (tid < 6)   st2[tid] = stk[tid];

    float az0 = 0.f, az1 = 0.f, az2 = 0.f;     // A(t-1) for gates at CA(tl)
    float xv = 0.f;
    __syncthreads();   // prologue LDS visible

    for (int tl = 0; tl < TC; ++tl) {
        const int t = t0 + tl;

        // ======== phase CA: gates(t-1)+publish | KAN(t) | poll h(t-1) | x(t+1) ========
        if (pstate) {
            if (tl > 0) {
                float z0 = az0, z1 = az1, z2 = az2;
#pragma unroll
                for (int q = 0; q < 4; ++q) {
                    z0 += zred[w + q][lane][0];
                    z1 += zred[w + q][lane][1];
                    z2 += zred[w + q][lane][2];
                }
                float ig = sigm(z0);
                float fg = sigm(z1);
                c_reg = fg * c_reg + ig * tanh_fast(z2);
                float og = sigm(so_l[0] * aw0 + so_l[1] * aw1 + so_l[2] * aw2 + ab);
                float hn = og * tanh_fast(c_reg);
                hs[ui] = hn;
                hhist[tl - 1][c] = hn;
                // sentinel publish of h(s), s = t-1: low mantissa bit := (s>>1)&1.
                // Fire-and-forget: no drain, no flag. Data self-announces.
                unsigned hb = (__float_as_uint(hn) & ~1u) | (unsigned)(((t - 1) >> 1) & 1);
                __hip_atomic_store((unsigned*)&xh[((size_t)b * 2 + ((t - 1) & 1)) * 256 + ui],
                                   hb, __ATOMIC_RELAXED, __HIP_MEMORY_SCOPE_SYSTEM);
            }
            // A(t) prefetch for gates at CA(tl+1)
            const float* Ap = A + ((size_t)b * TC + tl) * TU + ui;
            az0 = Ap[0]; az1 = Ap[256]; az2 = Ap[512];
        }
        if (u1i >= 0) {                           // x(t+1) issue (stage at B)
            int tn = (t + 1 < T_) ? t + 1 : t;
            xv = X[((size_t)b * T_ + tn) * D_ + u1i];
        }
        {                                         // KAN u0 (reads xs(t), subs)
            float a0 = xs[d0] * skx0 + subs[s0] * skh0;
            kred[tid] = a0 * sigm(a0) * bw0 + spline_eval(a0, ksw_lds, tid);
        }
        if (u1i >= 0) {                           // KAN u1
            float a1 = xs[u1i] * skx1 + subs[2] * skh1;
            kred[512 + u1i] = a1 * sigm(a1) * bw1 + spline_eval(a1, ksw_lds, 512 + u1i);
        }
        if (tl > 0 && tid >= 384) {               // waves 6,7: sentinel poll = data fetch
            const int uidx = (1 - r) * 128 + (tid - 384);
            const unsigned expect = (unsigned)(((t - 1) >> 1) & 1);
            const unsigned* src = (const unsigned*)&xh[((size_t)b * 2 + ((t - 1) & 1)) * 256 + uidx];
            unsigned v;
            do {
                v = __hip_atomic_load(src, __ATOMIC_RELAXED, __HIP_MEMORY_SCOPE_SYSTEM);
            } while ((v & 1u) != expect);
            hs[uidx] = __uint_as_float(v);
        }
        __syncthreads();   // syncCA: hs(t-1) complete + kred visible

        // ======== phase B: GEMV(t) | KAN reduce(t) | stage xs(t+1) ========
        {
            const float* hp = &hs[p * 64];
            float a0 = 0.f, a1 = 0.f, a2 = 0.f;
#pragma unroll
            for (int j = 0; j < 16; ++j) {
                float4 h4 = *(const float4*)(hp + j * 4);   // uniform addr -> LDS broadcast
                a0 = fmaf(h4.x, Rf[0][j * 4 + 0], a0);
                a1 = fmaf(h4.x, Rf[1][j * 4 + 0], a1);
                a2 = fmaf(h4.x, Rf[2][j * 4 + 0], a2);
                a0 = fmaf(h4.y, Rf[0][j * 4 + 1], a0);
                a1 = fmaf(h4.y, Rf[1][j * 4 + 1], a1);
                a2 = fmaf(h4.y, Rf[2][j * 4 + 1], a2);
                a0 = fmaf(h4.z, Rf[0][j * 4 + 2], a0);
                a1 = fmaf(h4.z, Rf[1][j * 4 + 2], a1);
                a2 = fmaf(h4.z, Rf[2][j * 4 + 2], a2);
                a0 = fmaf(h4.w, Rf[0][j * 4 + 3], a0);
                a1 = fmaf(h4.w, Rf[1][j * 4 + 3], a1);
                a2 = fmaf(h4.w, Rf[2][j * 4 + 3], a2);
            }
            zred[w][lane][0] = a0;
            zred[w][lane][1] = a1;
            zred[w][lane][2] = a2;
        }
        if (w < 3) {                              // KAN reduce (kred from syncCA)
            float v = kred[w * 256 + lane] + kred[w * 256 + 64 + lane]
                    + kred[w * 256 + 128 + lane] + kred[w * 256 + 192 + lane];
#pragma unroll
            for (int m = 32; m > 0; m >>= 1) v += __shfl_xor(v, m, 64);
            if (lane == 0) {
                so_l[w] = v;
                subs[w] = st2[w * 2] * v + st2[w * 2 + 1] * subs[w];
            }
        }
        if (u1i >= 0) xs[u1i] = xv;               // stage x(t+1)
        __syncthreads();   // syncB: zred/so_l/subs/xs(t+1) visible
    }

    // ---- epilogue: final gates (step s = t0+TC-1), then bulk out-write ----
    if (pstate) {
        float z0 = az0, z1 = az1, z2 = az2;       // az = A(t0+TC-1)
#pragma unroll
        for (int q = 0; q < 4; ++q) {
            z0 += zred[w + q][lane][0];
            z1 += zred[w + q][lane][1];
            z2 += zred[w + q][lane][2];
        }
        float ig = sigm(z0);
        float fg = sigm(z1);
        c_reg = fg * c_reg + ig * tanh_fast(z2);
        float og = sigm(so_l[0] * aw0 + so_l[1] * aw1 + so_l[2] * aw2 + ab);
        float hn = og * tanh_fast(c_reg);
        hhist[TC - 1][c] = hn;
        ws_h[b * 256 + ui] = hn;                  // exact value for next chunk's prologue
        ws_c[b * 256 + ui] = c_reg;
        // tagged publish of h(t0+TC-1) keeps per-word tag alternation unbroken
        // across chunk boundaries (R9 fix -- REQUIRED for correctness).
        {
            const int s = t0 + TC - 1;
            unsigned hb = (__float_as_uint(hn) & ~1u) | (unsigned)(((s) >> 1) & 1);
            __hip_atomic_store((unsigned*)&xh[((size_t)b * 2 + (s & 1)) * 256 + ui],
                               hb, __ATOMIC_RELAXED, __HIP_MEMORY_SCOPE_SYSTEM);
        }
    }
    __syncthreads();
    for (int i = tid; i < TC * 128; i += 512) {
        int tl = i >> 7, cc = i & 127;
        out[((size_t)b * T_ + t0 + tl) * U_ + r * 128 + cc] = hhist[tl][cc];
    }
    if (tid < 3) ws_sub[b * 3 + tid] = subs[tid];
}

extern "C" void kernel_launch(void* const* d_in, const int* in_sizes, int n_in,
                              void* d_out, int out_size, void* d_ws, size_t ws_size,
                              hipStream_t stream) {
    const float* x    = (const float*)d_in[0];
    const float* Kmat = (const float*)d_in[1];
    const float* R    = (const float*)d_in[2];
    const float* bias = (const float*)d_in[3];
    const float* stk  = (const float*)d_in[4];
    const float* strk = (const float*)d_in[5];
    const float* aggw = (const float*)d_in[6];
    const float* aggb = (const float*)d_in[7];
    const float* kbw  = (const float*)d_in[8];
    const float* ksw  = (const float*)d_in[9];
    float* out = (float*)d_out;

    float* ws   = (float*)d_ws;
    float* A    = ws;                             // 6,291,456 floats (24 MB)
    float* wh   = A + (size_t)B_ * TC * TU;       // 32768
    float* wc   = wh + B_ * U_;                   // 32768
    float* wsub = wc + B_ * U_;                   // 384 (pad to 512)
    float* xh   = wsub + 512;                     // B*2*256 = 65536

    k0_init<<<dim3(B_), dim3(256), 0, stream>>>(wh, wc, wsub, xh);
    for (int ci = 0; ci < NC; ++ci) {
        k1_gemm<<<dim3((B_ * TC) / 64, TU / 192), dim3(128), 0, stream>>>(x, Kmat, bias, A, ci * TC);
        k2_rec<<<dim3(2 * B_), dim3(512), 0, stream>>>(A, x, R, stk, strk, aggw, aggb, kbw, ksw,
                                                       out, wh, wc, wsub, xh, ci * TC);
    }
}

// Round 12
// 789.066 us; speedup vs baseline: 1.2047x; 1.1374x over previous
//
#include <hip/hip_runtime.h>

#define B_  128
#define T_  256
#define D_  256
#define U_  256
#define TU  768      // 3*U
#define TC  64       // timestep chunk
#define NC  (T_/TC)  // 4 chunks

__device__ __forceinline__ float sigm(float x) { return 1.f / (1.f + __expf(-x)); }

// tanh via __expf: tanh(x) = 1 - 2/(e^{2x}+1). (absmax unchanged since R2)
__device__ __forceinline__ float tanh_fast(float x) {
    float e = __expf(2.f * x);
    return 1.f - 2.f / (e + 1.f);
}

// direct cubic B-spline eval: grid cells [g_j, g_j+0.4), g_j = -2.2 + 0.4*j, j=0..10
// nonzero basis m = j-3..j (clipped to 0..7); coeffs at ksw_lds[u*9 + m]
__device__ __forceinline__ float spline_eval(float x, const float* __restrict__ ksw_lds, int u) {
    float xc = (x + 2.2f) * 2.5f;
    float fj = floorf(xc);
    int   j  = (int)fj;
    float tl = xc - fj;
    float t2 = tl * tl, t3 = t2 * tl;
    float om = 1.f - tl;
    const float S = 1.f / 6.f;
    float w0 = om * om * om * S;                            // m = j-3
    float w1 = (3.f * t3 - 6.f * t2 + 4.f) * S;             // m = j-2
    float w2 = (-3.f * t3 + 3.f * t2 + 3.f * tl + 1.f) * S; // m = j-1
    float w3 = t3 * S;                                      // m = j
    bool  v  = (j >= 0) && (j <= 10);
    float r  = 0.f;
#pragma unroll
    for (int k = 0; k < 4; ++k) {
        int   m  = j - 3 + k;
        bool  ok = v && (m >= 0) && (m <= 7);
        int   mc = min(max(m, 0), 7);
        float wk = (k == 0) ? w0 : (k == 1) ? w1 : (k == 2) ? w2 : w3;
        float cf = ksw_lds[u * 9 + mc];
        r += ok ? wk * cf : 0.f;
    }
    return r;
}

// ---------------- K0: zero recurrent state + poison xh tags ----------------
__global__ void k0_init(float* __restrict__ wh, float* __restrict__ wc,
                        float* __restrict__ wsub, float* __restrict__ xh) {
    int i = blockIdx.x * 256 + threadIdx.x;          // grid 128 -> 32768
    wh[i] = 0.f;
    wc[i] = 0.f;
    ((int*)xh)[i]         = 1;
    ((int*)xh)[i + 32768] = 1;
    if (i < 3 * B_) wsub[i] = 0.f;
}

// ---------------- K1: A[b][tl][j] = x[b, t0+tl, :] @ kernel + bias ----------------
// ROUND 12: 64x128 tile / 256 thr / 4x8 acc (best-measured geometry: 768 blocks
// = 3/CU = 12 waves/CU) + DOUBLE-BUFFERED LDS staging. R10's measurement (53us
// vs 20.5us FMA floor) showed ~60% of k1 time was staging exposure: each
// k-block's global loads were issued right before the barrier that consumes
// them (vmcnt(0) drain ~500cyc x 16 kb). Now: kb+1's loads are issued into
// registers at the TOP of kb's compute (latency hides under 64cyc x 16 FMA),
// written to the alternate LDS buffer after compute, ONE barrier per k-block.
// R11's 128-thr retile (80us) taught: never drop below 2 waves/SIMD.
__global__ __launch_bounds__(256) void k1_gemm(const float* __restrict__ X,
                                               const float* __restrict__ Km,
                                               const float* __restrict__ bias,
                                               float* __restrict__ A, int t0) {
    __shared__ float Xs[2][16][68];    // 8.7 KB
    __shared__ float Ks[2][16][132];   // 16.9 KB
    const int tid = threadIdx.x;
    const int bm  = blockIdx.x * 64;
    const int bn  = blockIdx.y * 128;

    // compute mapping: 16x16 threads; 4 rows x 8 cols (two 4-col groups)
    const int ty = tid >> 4, tx = tid & 15;
    const int m0 = ty * 4, n0 = tx * 4;

    // X staging: row xr = tid&63, k-quarter kq = (tid>>6)*4; 1 float4/thread
    const int xr = tid & 63, kq = (tid >> 6) * 4;
    const int rr = bm + xr;
    const float* xrow = X + (size_t)((rr >> 6) * T_ + t0 + (rr & 63)) * D_;

    // K staging: k-row kr = tid>>4, col group nq = (tid&15)*8; 2 float4/thread
    const int kr = tid >> 4, nq = (tid & 15) * 8;
    const float* krow = Km + (size_t)kr * TU + bn + nq;

    // prologue: stage kb=0 into buffer 0
    {
        float4 xv  = *(const float4*)(xrow + kq);
        float4 kv0 = *(const float4*)(krow);
        float4 kv1 = *(const float4*)(krow + 4);
        Xs[0][kq + 0][xr] = xv.x; Xs[0][kq + 1][xr] = xv.y;
        Xs[0][kq + 2][xr] = xv.z; Xs[0][kq + 3][xr] = xv.w;
        *(float4*)&Ks[0][kr][nq]     = kv0;
        *(float4*)&Ks[0][kr][nq + 4] = kv1;
    }
    __syncthreads();

    float acc[4][8] = {};
    for (int kb = 0; kb < 16; ++kb) {
        const int cur = kb & 1;
        // issue kb+1 global loads NOW (latency hides under the FMA block)
        float4 xv, kv0, kv1;
        if (kb + 1 < 16) {
            const float* xp = xrow + (kb + 1) * 16 + kq;
            const float* kp = krow + (size_t)(kb + 1) * 16 * TU;
            xv  = *(const float4*)(xp);
            kv0 = *(const float4*)(kp);
            kv1 = *(const float4*)(kp + 4);
        }
        // compute on buf[cur]
#pragma unroll
        for (int k = 0; k < 16; ++k) {
            float4 av = *(float4*)&Xs[cur][k][m0];        // 16-way broadcast
            float4 b0 = *(float4*)&Ks[cur][k][n0];        // <=2-way banks
            float4 b1 = *(float4*)&Ks[cur][k][64 + n0];
            float a[4]  = {av.x, av.y, av.z, av.w};
            float bb[8] = {b0.x, b0.y, b0.z, b0.w, b1.x, b1.y, b1.z, b1.w};
#pragma unroll
            for (int i = 0; i < 4; ++i)
#pragma unroll
                for (int j = 0; j < 8; ++j)
                    acc[i][j] = fmaf(a[i], bb[j], acc[i][j]);
        }
        // write kb+1 into the other buffer, one barrier per k-block
        if (kb + 1 < 16) {
            const int nxt = cur ^ 1;
            Xs[nxt][kq + 0][xr] = xv.x; Xs[nxt][kq + 1][xr] = xv.y;
            Xs[nxt][kq + 2][xr] = xv.z; Xs[nxt][kq + 3][xr] = xv.w;
            *(float4*)&Ks[nxt][kr][nq]     = kv0;
            *(float4*)&Ks[nxt][kr][nq + 4] = kv1;
            __syncthreads();
        }
    }
    float4 bv0 = *(const float4*)(bias + bn + n0);
    float4 bv1 = *(const float4*)(bias + bn + 64 + n0);
#pragma unroll
    for (int i = 0; i < 4; ++i) {
        float4 o0, o1;
        o0.x = acc[i][0] + bv0.x; o0.y = acc[i][1] + bv0.y;
        o0.z = acc[i][2] + bv0.z; o0.w = acc[i][3] + bv0.w;
        o1.x = acc[i][4] + bv1.x; o1.y = acc[i][5] + bv1.y;
        o1.z = acc[i][6] + bv1.z; o1.w = acc[i][7] + bv1.w;
        *(float4*)(A + (size_t)(bm + m0 + i) * TU + bn + n0)      = o0;
        *(float4*)(A + (size_t)(bm + m0 + i) * TU + bn + 64 + n0) = o1;
    }
}

// ---------------- K2: pair-split recurrence, R stationary in regs ----------------
// BYTE-EXACT R9 kernel (141 us, verified twice: R9 and R11). Do not reorder:
// the polling waves' KAN eval must run BETWEEN poll-issue sites so it overlaps
// the partner's publish flight (R10's poll-first reorder cost +41 us).
__global__ __launch_bounds__(512, 2)
void k2_rec(const float* __restrict__ A,
            const float* __restrict__ X,
            const float* __restrict__ R,
            const float* __restrict__ stk,
            const float* __restrict__ strk,
            const float* __restrict__ aggw,
            const float* __restrict__ aggb,
            const float* __restrict__ kbw,
            const float* __restrict__ ksw,
            float* __restrict__ out,
            float* __restrict__ ws_h,
            float* __restrict__ ws_c,
            float* __restrict__ ws_sub,
            float* __restrict__ xh,    // [B][2][256], sentinel-tagged
            int t0) {
    __shared__ float hs[256];
    __shared__ float xs[256];
    __shared__ float zred[8][64][3];
    __shared__ float kred[768];
    __shared__ float so_l[3];
    __shared__ float subs[3];
    __shared__ float st2[6];
    __shared__ float hhist[TC][128];        // 32 KB h history -> epilogue bulk write
    __shared__ float ksw_lds[768 * 9];

    const int tid  = threadIdx.x;
    const int lane = tid & 63;
    const int w    = tid >> 6;
    const int p    = w & 3;
    const int c    = ((w >> 2) << 6) | lane;   // 0..127
    const int b    = blockIdx.x & 127;
    const int r    = blockIdx.x >> 7;
    const int ui   = r * 128 + c;              // global output-unit index
    const bool pstate = (p == 0);              // waves 0 and 4 hold gate state

    // ---- stationary R fragment (lives in unified VGPR/AGPR file) ----
    float Rf[3][64];
#pragma unroll
    for (int g = 0; g < 3; ++g)
#pragma unroll
        for (int uu = 0; uu < 64; ++uu)
            Rf[g][uu] = R[(size_t)(p * 64 + uu) * TU + g * 256 + ui];

    // ---- KAN duties: u0 = tid for ALL; u1 + x-prefetch on waves 1,2,3,5 ----
    const int s0 = tid >> 8, d0 = tid & 255;
    const float skx0 = strk[s0 * 512 + d0];
    const float skh0 = strk[s0 * 512 + 256 + d0];
    const float bw0  = kbw[tid];
    int u1i = -1;
    if (tid >= 64 && tid < 256)       u1i = tid - 64;    // waves 1-3 -> 0..191
    else if (tid >= 320 && tid < 384) u1i = tid - 128;   // wave 5    -> 192..255
    float skx1 = 0.f, skh1 = 0.f, bw1 = 0.f;
    if (u1i >= 0) {
        skx1 = strk[2 * 512 + u1i];
        skh1 = strk[2 * 512 + 256 + u1i];
        bw1  = kbw[512 + u1i];
    }

    const float aw0 = aggw[ui], aw1 = aggw[256 + ui], aw2 = aggw[512 + ui], ab = aggb[ui];
    float c_reg = ws_c[b * 256 + ui];

    for (int i = tid; i < 768 * 8; i += 512) ksw_lds[(i >> 3) * 9 + (i & 7)] = ksw[i];
    if (tid < 256) hs[tid] = ws_h[b * 256 + tid];
    if (tid < 256) xs[tid] = X[((size_t)b * T_ + t0) * D_ + tid];
    if (tid < 3)   subs[tid] = ws_sub[b * 3 + tid];
    if (tid < 6)   st2[tid] = stk[tid];

    float az0 = 0.f, az1 = 0.f, az2 = 0.f;     // A(t-1) for gates at CA(tl)
    float xv = 0.f;
    __syncthreads();   // prologue LDS visible

    for (int tl = 0; tl < TC; ++tl) {
        const int t = t0 + tl;

        // ======== phase CA: gates(t-1)+publish | KAN(t) | poll h(t-1) | x(t+1) ========
        if (pstate) {
            if (tl > 0) {
                float z0 = az0, z1 = az1, z2 = az2;
#pragma unroll
                for (int q = 0; q < 4; ++q) {
                    z0 += zred[w + q][lane][0];
                    z1 += zred[w + q][lane][1];
                    z2 += zred[w + q][lane][2];
                }
                float ig = sigm(z0);
                float fg = sigm(z1);
                c_reg = fg * c_reg + ig * tanh_fast(z2);
                float og = sigm(so_l[0] * aw0 + so_l[1] * aw1 + so_l[2] * aw2 + ab);
                float hn = og * tanh_fast(c_reg);
                hs[ui] = hn;
                hhist[tl - 1][c] = hn;
                // sentinel publish of h(s), s = t-1: low mantissa bit := (s>>1)&1.
                // Fire-and-forget: no drain, no flag. Data self-announces.
                unsigned hb = (__float_as_uint(hn) & ~1u) | (unsigned)(((t - 1) >> 1) & 1);
                __hip_atomic_store((unsigned*)&xh[((size_t)b * 2 + ((t - 1) & 1)) * 256 + ui],
                                   hb, __ATOMIC_RELAXED, __HIP_MEMORY_SCOPE_SYSTEM);
            }
            // A(t) prefetch for gates at CA(tl+1)
            const float* Ap = A + ((size_t)b * TC + tl) * TU + ui;
            az0 = Ap[0]; az1 = Ap[256]; az2 = Ap[512];
        }
        if (u1i >= 0) {                           // x(t+1) issue (stage at B)
            int tn = (t + 1 < T_) ? t + 1 : t;
            xv = X[((size_t)b * T_ + tn) * D_ + u1i];
        }
        {                                         // KAN u0 (reads xs(t), subs)
            float a0 = xs[d0] * skx0 + subs[s0] * skh0;
            kred[tid] = a0 * sigm(a0) * bw0 + spline_eval(a0, ksw_lds, tid);
        }
        if (u1i >= 0) {                           // KAN u1
            float a1 = xs[u1i] * skx1 + subs[2] * skh1;
            kred[512 + u1i] = a1 * sigm(a1) * bw1 + spline_eval(a1, ksw_lds, 512 + u1i);
        }
        if (tl > 0 && tid >= 384) {               // waves 6,7: sentinel poll = data fetch
            const int uidx = (1 - r) * 128 + (tid - 384);
            const unsigned expect = (unsigned)(((t - 1) >> 1) & 1);
            const unsigned* src = (const unsigned*)&xh[((size_t)b * 2 + ((t - 1) & 1)) * 256 + uidx];
            unsigned v;
            do {
                v = __hip_atomic_load(src, __ATOMIC_RELAXED, __HIP_MEMORY_SCOPE_SYSTEM);
            } while ((v & 1u) != expect);
            hs[uidx] = __uint_as_float(v);
        }
        __syncthreads();   // syncCA: hs(t-1) complete + kred visible

        // ======== phase B: GEMV(t) | KAN reduce(t) | stage xs(t+1) ========
        {
            const float* hp = &hs[p * 64];
            float a0 = 0.f, a1 = 0.f, a2 = 0.f;
#pragma unroll
            for (int j = 0; j < 16; ++j) {
                float4 h4 = *(const float4*)(hp + j * 4);   // uniform addr -> LDS broadcast
                a0 = fmaf(h4.x, Rf[0][j * 4 + 0], a0);
                a1 = fmaf(h4.x, Rf[1][j * 4 + 0], a1);
                a2 = fmaf(h4.x, Rf[2][j * 4 + 0], a2);
                a0 = fmaf(h4.y, Rf[0][j * 4 + 1], a0);
                a1 = fmaf(h4.y, Rf[1][j * 4 + 1], a1);
                a2 = fmaf(h4.y, Rf[2][j * 4 + 1], a2);
                a0 = fmaf(h4.z, Rf[0][j * 4 + 2], a0);
                a1 = fmaf(h4.z, Rf[1][j * 4 + 2], a1);
                a2 = fmaf(h4.z, Rf[2][j * 4 + 2], a2);
                a0 = fmaf(h4.w, Rf[0][j * 4 + 3], a0);
                a1 = fmaf(h4.w, Rf[1][j * 4 + 3], a1);
                a2 = fmaf(h4.w, Rf[2][j * 4 + 3], a2);
            }
            zred[w][lane][0] = a0;
            zred[w][lane][1] = a1;
            zred[w][lane][2] = a2;
        }
        if (w < 3) {                              // KAN reduce (kred from syncCA)
            float v = kred[w * 256 + lane] + kred[w * 256 + 64 + lane]
                    + kred[w * 256 + 128 + lane] + kred[w * 256 + 192 + lane];
#pragma unroll
            for (int m = 32; m > 0; m >>= 1) v += __shfl_xor(v, m, 64);
            if (lane == 0) {
                so_l[w] = v;
                subs[w] = st2[w * 2] * v + st2[w * 2 + 1] * subs[w];
            }
        }
        if (u1i >= 0) xs[u1i] = xv;               // stage x(t+1)
        __syncthreads();   // syncB: zred/so_l/subs/xs(t+1) visible
    }

    // ---- epilogue: final gates (step s = t0+TC-1), then bulk out-write ----
    if (pstate) {
        float z0 = az0, z1 = az1, z2 = az2;       // az = A(t0+TC-1)
#pragma unroll
        for (int q = 0; q < 4; ++q) {
            z0 += zred[w + q][lane][0];
            z1 += zred[w + q][lane][1];
            z2 += zred[w + q][lane][2];
        }
        float ig = sigm(z0);
        float fg = sigm(z1);
        c_reg = fg * c_reg + ig * tanh_fast(z2);
        float og = sigm(so_l[0] * aw0 + so_l[1] * aw1 + so_l[2] * aw2 + ab);
        float hn = og * tanh_fast(c_reg);
        hhist[TC - 1][c] = hn;
        ws_h[b * 256 + ui] = hn;                  // exact value for next chunk's prologue
        ws_c[b * 256 + ui] = c_reg;
        // tagged publish of h(t0+TC-1) keeps per-word tag alternation unbroken
        // across chunk boundaries (R9 fix -- REQUIRED for correctness).
        {
            const int s = t0 + TC - 1;
            unsigned hb = (__float_as_uint(hn) & ~1u) | (unsigned)(((s) >> 1) & 1);
            __hip_atomic_store((unsigned*)&xh[((size_t)b * 2 + (s & 1)) * 256 + ui],
                               hb, __ATOMIC_RELAXED, __HIP_MEMORY_SCOPE_SYSTEM);
        }
    }
    __syncthreads();
    for (int i = tid; i < TC * 128; i += 512) {
        int tl = i >> 7, cc = i & 127;
        out[((size_t)b * T_ + t0 + tl) * U_ + r * 128 + cc] = hhist[tl][cc];
    }
    if (tid < 3) ws_sub[b * 3 + tid] = subs[tid];
}

extern "C" void kernel_launch(void* const* d_in, const int* in_sizes, int n_in,
                              void* d_out, int out_size, void* d_ws, size_t ws_size,
                              hipStream_t stream) {
    const float* x    = (const float*)d_in[0];
    const float* Kmat = (const float*)d_in[1];
    const float* R    = (const float*)d_in[2];
    const float* bias = (const float*)d_in[3];
    const float* stk  = (const float*)d_in[4];
    const float* strk = (const float*)d_in[5];
    const float* aggw = (const float*)d_in[6];
    const float* aggb = (const float*)d_in[7];
    const float* kbw  = (const float*)d_in[8];
    const float* ksw  = (const float*)d_in[9];
    float* out = (float*)d_out;

    float* ws   = (float*)d_ws;
    float* A    = ws;                             // 6,291,456 floats (24 MB)
    float* wh   = A + (size_t)B_ * TC * TU;       // 32768
    float* wc   = wh + B_ * U_;                   // 32768
    float* wsub = wc + B_ * U_;                   // 384 (pad to 512)
    float* xh   = wsub + 512;                     // B*2*256 = 65536

    k0_init<<<dim3(B_), dim3(256), 0, stream>>>(wh, wc, wsub, xh);
    for (int ci = 0; ci < NC; ++ci) {
        k1_gemm<<<dim3((B_ * TC) / 64, TU / 128), dim3(256), 0, stream>>>(x, Kmat, bias, A, ci * TC);
        k2_rec<<<dim3(2 * B_), dim3(512), 0, stream>>>(A, x, R, stk, strk, aggw, aggb, kbw, ksw,
                                                       out, wh, wc, wsub, xh, ci * TC);
    }
}